// Round 9
// baseline (898.163 us; speedup 1.0000x reference)
//
#include <hip/hip_runtime.h>
#include <math.h>

#define N_NODES 50000
#define N_EDGES 800000
#define HID 128
#define H2 256
#define STEPS 12
#define DT 0.5f

#define SCAN_B 256
#define NB ((N_NODES + SCAN_B - 1) / SCAN_B)   // 196
#define NODE_BLOCKS ((N_NODES + 31) / 32)      // 1563
#define N_PAD (NODE_BLOCKS * 32)               // 50016

typedef __attribute__((ext_vector_type(8))) short bf16x8;
typedef __attribute__((ext_vector_type(4))) float f32x4;
typedef __attribute__((ext_vector_type(2))) float f32x2;

__device__ inline unsigned short f2bf(float x) {
    unsigned int u = __float_as_uint(x);
    unsigned int r = (u + 0x7FFFu + ((u >> 16) & 1u)) >> 16;  // round-nearest-even
    return (unsigned short)r;
}
__device__ inline float bf2f(unsigned short b) {
    return __uint_as_float(((unsigned int)b) << 16);
}
__device__ inline float u2f(unsigned int u) { return __uint_as_float(u); }

// ---------------- CSR build ----------------

__global__ void k_zero_counts(int* __restrict__ counts) {
    int i = blockIdx.x * 256 + threadIdx.x;
    if (i < N_NODES) counts[i] = 0;
}

__global__ void k_hist(const int* __restrict__ dst, int* __restrict__ counts) {
    int e = blockIdx.x * 256 + threadIdx.x;
    if (e < N_EDGES) atomicAdd(&counts[dst[e]], 1);
}

__global__ void k_blocksum(const int* __restrict__ counts, int* __restrict__ bsum) {
    __shared__ int s[SCAN_B];
    int idx = blockIdx.x * SCAN_B + threadIdx.x;
    int v = (idx < N_NODES) ? counts[idx] : 0;
    s[threadIdx.x] = v;
    __syncthreads();
    for (int off = SCAN_B / 2; off > 0; off >>= 1) {
        if (threadIdx.x < off) s[threadIdx.x] += s[threadIdx.x + off];
        __syncthreads();
    }
    if (threadIdx.x == 0) bsum[blockIdx.x] = s[0];
}

// parallel exclusive scan of the NB block sums (was: 1-thread serial loop,
// ~196 dependent global loads = 15-25us fixed overhead)
__global__ void k_scan_par(int* __restrict__ bsum, int* __restrict__ offsets) {
    __shared__ int s[SCAN_B];
    int t = threadIdx.x;
    int v = (t < NB) ? bsum[t] : 0;
    s[t] = v;
    __syncthreads();
    for (int off = 1; off < SCAN_B; off <<= 1) {
        int tv = 0;
        if (t >= off) tv = s[t - off];
        __syncthreads();
        s[t] += tv;
        __syncthreads();
    }
    if (t < NB) bsum[t] = s[t] - v;   // exclusive prefix
    if (t == 0) offsets[N_NODES] = N_EDGES;
}

__global__ void k_offsets(const int* __restrict__ counts, const int* __restrict__ bsum,
                          int* __restrict__ offsets, int* __restrict__ cursor) {
    __shared__ int s[SCAN_B];
    int idx = blockIdx.x * SCAN_B + threadIdx.x;
    int v = (idx < N_NODES) ? counts[idx] : 0;
    s[threadIdx.x] = v;
    __syncthreads();
    for (int off = 1; off < SCAN_B; off <<= 1) {
        int t = 0;
        if ((int)threadIdx.x >= off) t = s[threadIdx.x - off];
        __syncthreads();
        s[threadIdx.x] += t;
        __syncthreads();
    }
    if (idx < N_NODES) {
        int excl = s[threadIdx.x] - v;
        int o = bsum[blockIdx.x] + excl;
        offsets[idx] = o;
        cursor[idx]  = o;
    }
}

__global__ void k_scatter(const int* __restrict__ src, const int* __restrict__ dst,
                          int* __restrict__ cursor, int* __restrict__ csr_src) {
    int e = blockIdx.x * 256 + threadIdx.x;
    if (e < N_EDGES) {
        int d = dst[e];
        int p = atomicAdd(&cursor[d], 1);
        csr_src[p] = src[e];
    }
}

// ---------------- weight pack: f32 [K][N] -> hi/lo bf16 in B-fragment order ----------------

__global__ void k_pack(const float* __restrict__ W, int K, int N,
                       unsigned short* __restrict__ hi, unsigned short* __restrict__ lo) {
    int KT = K >> 5, NT = N >> 4;
    int t = blockIdx.x * 256 + threadIdx.x;
    if (t >= KT * NT * 64) return;
    int l = t & 63, tile = t >> 6;
    int kt = tile % KT, nt = tile / KT;
    int n  = nt * 16 + (l & 15);
    int k0 = kt * 32 + (l >> 4) * 8;
    int base = ((nt * KT + kt) * 64 + l) * 8;
    for (int j = 0; j < 8; j++) {
        float w = W[(size_t)(k0 + j) * N + n];
        unsigned short h = f2bf(w);
        hi[base + j] = h;
        lo[base + j] = f2bf(w - bf2f(h));
    }
}

// ---------------- h0 = tanh(gat @ W_in + b_in), MFMA ----------------

__global__ __launch_bounds__(256, 3) void k_h0_mfma(
    const float* __restrict__ gat,
    const unsigned short* __restrict__ wh, const unsigned short* __restrict__ wl,
    const float* __restrict__ b_in, float* __restrict__ h,
    unsigned short* __restrict__ hbf) {
    __shared__ unsigned short Ahi[32][136];
    __shared__ unsigned short Alo[32][136];
    int tid = threadIdx.x;
    int node0 = blockIdx.x * 32;

    for (int idx = tid; idx < 32 * 64; idx += 256) {
        int m = idx >> 6, c = (idx & 63) * 2;
        float2 v;
        if (node0 + m < N_NODES) v = *(const float2*)&gat[(size_t)(node0 + m) * 128 + c];
        else { v.x = 0.f; v.y = 0.f; }
        unsigned short h0 = f2bf(v.x), h1 = f2bf(v.y);
        unsigned short l0 = f2bf(v.x - bf2f(h0)), l1 = f2bf(v.y - bf2f(h1));
        *(unsigned int*)&Ahi[m][c] = (unsigned int)h0 | ((unsigned int)h1 << 16);
        *(unsigned int*)&Alo[m][c] = (unsigned int)l0 | ((unsigned int)l1 << 16);
    }
    __syncthreads();

    int l = tid & 63, wv = tid >> 6;
    int c15 = l & 15, q = l >> 4;
    f32x4 acc[2][2] = {};
#pragma unroll
    for (int kt = 0; kt < 4; kt++) {
        bf16x8 ah[2], al[2];
#pragma unroll
        for (int mt = 0; mt < 2; mt++) {
            ah[mt] = *(const bf16x8*)&Ahi[mt * 16 + c15][kt * 32 + q * 8];
            al[mt] = *(const bf16x8*)&Alo[mt * 16 + c15][kt * 32 + q * 8];
        }
#pragma unroll
        for (int nn = 0; nn < 2; nn++) {
            int nt = wv * 2 + nn;
            bf16x8 bh = *(const bf16x8*)&wh[(size_t)((nt * 4 + kt) * 64 + l) * 8];
            bf16x8 bl = *(const bf16x8*)&wl[(size_t)((nt * 4 + kt) * 64 + l) * 8];
#pragma unroll
            for (int mt = 0; mt < 2; mt++) {
                acc[mt][nn] = __builtin_amdgcn_mfma_f32_16x16x32_bf16(ah[mt], bh, acc[mt][nn], 0, 0, 0);
                acc[mt][nn] = __builtin_amdgcn_mfma_f32_16x16x32_bf16(ah[mt], bl, acc[mt][nn], 0, 0, 0);
                acc[mt][nn] = __builtin_amdgcn_mfma_f32_16x16x32_bf16(al[mt], bh, acc[mt][nn], 0, 0, 0);
            }
        }
    }
#pragma unroll
    for (int nn = 0; nn < 2; nn++) {
        int col = (wv * 2 + nn) * 16 + c15;
        float bb = b_in[col];
#pragma unroll
        for (int mt = 0; mt < 2; mt++)
#pragma unroll
            for (int r = 0; r < 4; r++) {
                int node = node0 + mt * 16 + q * 4 + r;
                if (node < N_NODES) {
                    float v = tanhf(acc[mt][nn][r] + bb);
                    h[(size_t)node * 128 + col]   = v;
                    hbf[(size_t)node * 128 + col] = f2bf(v);
                }
            }
    }
}

// ---------------- fused step, 512 threads / 8 waves, M=32 ----------------
// Round-8 win kept. Round-9 deltas: packed f32x2 accumulate (v_pk_add_f32,
// 4->3 VALU per dword) + one-batch index prefetch in the gather loop.

__global__ __launch_bounds__(512, 4) void k_step(
    const unsigned short* __restrict__ hbf_in,
    float* __restrict__ h, unsigned short* __restrict__ hbf_out,
    const int* __restrict__ offsets, const int* __restrict__ csr,
    const unsigned short* __restrict__ w1h, const unsigned short* __restrict__ w1l,
    const float* __restrict__ b1,
    const unsigned short* __restrict__ w2h, const unsigned short* __restrict__ w2l,
    const float* __restrict__ b2, const float* __restrict__ clr) {
    __shared__ unsigned short Ahi[32][136];
    __shared__ unsigned short Alo[32][136];
    __shared__ unsigned short Y[32][264];
    int tid = threadIdx.x, l = tid & 63, wv = tid >> 6;   // wv 0..7
    int c15 = l & 15, q = l >> 4;
    int node0 = blockIdx.x * 32;
    int g  = l >> 4;       // edge group 0..3
    int cl = l & 15;       // col chunk: cols cl*8..+8

    // ---- Phase 1: segment-mean gather into LDS hi/lo planes (4 nodes/wave) ----
#pragma unroll 1
    for (int i = 0; i < 4; i++) {
        int m = wv * 4 + i;
        int node = node0 + m;
        f32x2 A0 = {0.f, 0.f}, A1 = {0.f, 0.f}, A2 = {0.f, 0.f}, A3 = {0.f, 0.f};
        auto accum = [&](uint4 w) {
            f32x2 v0 = { u2f(w.x << 16), u2f(w.x & 0xFFFF0000u) };
            f32x2 v1 = { u2f(w.y << 16), u2f(w.y & 0xFFFF0000u) };
            f32x2 v2 = { u2f(w.z << 16), u2f(w.z & 0xFFFF0000u) };
            f32x2 v3 = { u2f(w.w << 16), u2f(w.w & 0xFFFF0000u) };
            A0 += v0; A1 += v1; A2 += v2; A3 += v3;
        };
        int deg = 0;
        if (node < N_NODES) {
            int beg = offsets[node], end = offsets[node + 1];
            deg = end - beg;
            int e = beg + g;
            if (e + 12 < end) {
                int i0 = csr[e], i1 = csr[e + 4], i2 = csr[e + 8], i3 = csr[e + 12];
                uint4 w0 = *(const uint4*)&hbf_in[(size_t)i0 * 128 + cl * 8];
                uint4 w1 = *(const uint4*)&hbf_in[(size_t)i1 * 128 + cl * 8];
                uint4 w2 = *(const uint4*)&hbf_in[(size_t)i2 * 128 + cl * 8];
                uint4 w3 = *(const uint4*)&hbf_in[(size_t)i3 * 128 + cl * 8];
                e += 16;
                while (e + 12 < end) {
                    // prefetch next batch's indices+data before consuming current
                    int j0 = csr[e], j1 = csr[e + 4], j2 = csr[e + 8], j3 = csr[e + 12];
                    uint4 x0 = *(const uint4*)&hbf_in[(size_t)j0 * 128 + cl * 8];
                    uint4 x1 = *(const uint4*)&hbf_in[(size_t)j1 * 128 + cl * 8];
                    uint4 x2 = *(const uint4*)&hbf_in[(size_t)j2 * 128 + cl * 8];
                    uint4 x3 = *(const uint4*)&hbf_in[(size_t)j3 * 128 + cl * 8];
                    accum(w0); accum(w1); accum(w2); accum(w3);
                    w0 = x0; w1 = x1; w2 = x2; w3 = x3;
                    e += 16;
                }
                accum(w0); accum(w1); accum(w2); accum(w3);
            }
            for (; e < end; e += 4) {
                int i0 = csr[e];
                uint4 w0 = *(const uint4*)&hbf_in[(size_t)i0 * 128 + cl * 8];
                accum(w0);
            }
        }
        float a0 = A0.x, a1 = A0.y, a2 = A1.x, a3 = A1.y;
        float a4 = A2.x, a5 = A2.y, a6 = A3.x, a7 = A3.y;
        a0 += __shfl_xor(a0, 16); a1 += __shfl_xor(a1, 16);
        a2 += __shfl_xor(a2, 16); a3 += __shfl_xor(a3, 16);
        a4 += __shfl_xor(a4, 16); a5 += __shfl_xor(a5, 16);
        a6 += __shfl_xor(a6, 16); a7 += __shfl_xor(a7, 16);
        a0 += __shfl_xor(a0, 32); a1 += __shfl_xor(a1, 32);
        a2 += __shfl_xor(a2, 32); a3 += __shfl_xor(a3, 32);
        a4 += __shfl_xor(a4, 32); a5 += __shfl_xor(a5, 32);
        a6 += __shfl_xor(a6, 32); a7 += __shfl_xor(a7, 32);

        float inv = (deg > 1) ? 1.0f / (float)deg : 1.0f;
        float x0 = a0 * inv, x1 = a1 * inv, x2 = a2 * inv, x3 = a3 * inv;
        float x4 = a4 * inv, x5 = a5 * inv, x6 = a6 * inv, x7 = a7 * inv;
        unsigned short h0 = f2bf(x0), h1 = f2bf(x1), h2 = f2bf(x2), h3 = f2bf(x3);
        unsigned short h4 = f2bf(x4), h5 = f2bf(x5), h6 = f2bf(x6), h7 = f2bf(x7);
        if (g == 0) {
            uint4 o;
            o.x = (unsigned int)h0 | ((unsigned int)h1 << 16);
            o.y = (unsigned int)h2 | ((unsigned int)h3 << 16);
            o.z = (unsigned int)h4 | ((unsigned int)h5 << 16);
            o.w = (unsigned int)h6 | ((unsigned int)h7 << 16);
            *(uint4*)&Ahi[m][cl * 8] = o;
        } else if (g == 1) {
            unsigned short l0 = f2bf(x0 - bf2f(h0)), l1 = f2bf(x1 - bf2f(h1));
            unsigned short l2 = f2bf(x2 - bf2f(h2)), l3 = f2bf(x3 - bf2f(h3));
            unsigned short l4 = f2bf(x4 - bf2f(h4)), l5 = f2bf(x5 - bf2f(h5));
            unsigned short l6 = f2bf(x6 - bf2f(h6)), l7 = f2bf(x7 - bf2f(h7));
            uint4 o;
            o.x = (unsigned int)l0 | ((unsigned int)l1 << 16);
            o.y = (unsigned int)l2 | ((unsigned int)l3 << 16);
            o.z = (unsigned int)l4 | ((unsigned int)l5 << 16);
            o.w = (unsigned int)l6 | ((unsigned int)l7 << 16);
            *(uint4*)&Alo[m][cl * 8] = o;
        }
    }
    __syncthreads();

    // ---- Phase 2: GEMM1 [32x128]@[128x256], 3-product, 2 nt/wave ----
    {
        f32x4 acc1[2][2] = {};   // [mt][nn]
#pragma unroll
        for (int kt = 0; kt < 4; kt++) {
            bf16x8 ah[2], al[2];
#pragma unroll
            for (int mt = 0; mt < 2; mt++) {
                ah[mt] = *(const bf16x8*)&Ahi[mt * 16 + c15][kt * 32 + q * 8];
                al[mt] = *(const bf16x8*)&Alo[mt * 16 + c15][kt * 32 + q * 8];
            }
#pragma unroll
            for (int nn = 0; nn < 2; nn++) {
                int nt = wv * 2 + nn;
                bf16x8 bh = *(const bf16x8*)&w1h[(size_t)((nt * 4 + kt) * 64 + l) * 8];
                bf16x8 bl = *(const bf16x8*)&w1l[(size_t)((nt * 4 + kt) * 64 + l) * 8];
#pragma unroll
                for (int mt = 0; mt < 2; mt++) {
                    acc1[mt][nn] = __builtin_amdgcn_mfma_f32_16x16x32_bf16(ah[mt], bh, acc1[mt][nn], 0, 0, 0);
                    acc1[mt][nn] = __builtin_amdgcn_mfma_f32_16x16x32_bf16(ah[mt], bl, acc1[mt][nn], 0, 0, 0);
                    acc1[mt][nn] = __builtin_amdgcn_mfma_f32_16x16x32_bf16(al[mt], bh, acc1[mt][nn], 0, 0, 0);
                }
            }
        }
#pragma unroll
        for (int nn = 0; nn < 2; nn++) {
            int col = (wv * 2 + nn) * 16 + c15;
            float bb = b1[col];
#pragma unroll
            for (int mt = 0; mt < 2; mt++)
#pragma unroll
                for (int r = 0; r < 4; r++) {
                    int row = mt * 16 + q * 4 + r;
                    float x = acc1[mt][nn][r] + bb;
                    float gg = 0.5f * x * (1.0f + erff(x * 0.70710678118654752f));
                    Y[row][col] = f2bf(gg);
                }
        }
    }
    __syncthreads();

    // ---- Phase 3: GEMM2 [32x256]@[256x128], 2-product, 1 nt/wave ----
    f32x4 acc2[2] = {};   // [mt]
#pragma unroll
    for (int kt = 0; kt < 8; kt++) {
        bf16x8 ya[2];
#pragma unroll
        for (int mt = 0; mt < 2; mt++)
            ya[mt] = *(const bf16x8*)&Y[mt * 16 + c15][kt * 32 + q * 8];
        bf16x8 bh = *(const bf16x8*)&w2h[(size_t)((wv * 8 + kt) * 64 + l) * 8];
        bf16x8 bl = *(const bf16x8*)&w2l[(size_t)((wv * 8 + kt) * 64 + l) * 8];
#pragma unroll
        for (int mt = 0; mt < 2; mt++) {
            acc2[mt] = __builtin_amdgcn_mfma_f32_16x16x32_bf16(ya[mt], bh, acc2[mt], 0, 0, 0);
            acc2[mt] = __builtin_amdgcn_mfma_f32_16x16x32_bf16(ya[mt], bl, acc2[mt], 0, 0, 0);
        }
    }
    float decay = fmaxf(clr[0], 0.0f);
    {
        int col = wv * 16 + c15;
        float bb = b2[col];
#pragma unroll
        for (int mt = 0; mt < 2; mt++)
#pragma unroll
            for (int r = 0; r < 4; r++) {
                int node = node0 + mt * 16 + q * 4 + r;
                if (node < N_NODES) {
                    float hv = h[(size_t)node * 128 + col];
                    float diff = tanhf(acc2[mt][r] + bb);
                    float nh = hv + (diff - decay * hv) * DT;
                    h[(size_t)node * 128 + col]       = nh;
                    hbf_out[(size_t)node * 128 + col] = f2bf(nh);
                }
            }
    }
}

// ---------------- launch ----------------

extern "C" void kernel_launch(void* const* d_in, const int* in_sizes, int n_in,
                              void* d_out, int out_size, void* d_ws, size_t ws_size,
                              hipStream_t stream) {
    const float* gat   = (const float*)d_in[0];
    const int*   edges = (const int*)d_in[1];     // [2, E]: row0 = src, row1 = dst
    const float* W_in  = (const float*)d_in[2];
    const float* b_in  = (const float*)d_in[3];
    const float* W1    = (const float*)d_in[4];
    const float* b1    = (const float*)d_in[5];
    const float* W2    = (const float*)d_in[6];
    const float* b2    = (const float*)d_in[7];
    const float* clr   = (const float*)d_in[8];
    float* h = (float*)d_out;

    const int* src = edges;
    const int* dst = edges + N_EDGES;

    char* ws = (char*)d_ws;
    size_t off = 0;
    auto alloc = [&](size_t bytes) -> void* {
        off = (off + 255) & ~(size_t)255;
        void* p = ws + off;
        off += bytes;
        return p;
    };
    int*   counts  = (int*)alloc(sizeof(int) * N_NODES);
    int*   offsets = (int*)alloc(sizeof(int) * (N_NODES + 1));
    int*   cursor  = (int*)alloc(sizeof(int) * N_NODES);
    int*   bsum    = (int*)alloc(sizeof(int) * NB);
    int*   csr_src = (int*)alloc(sizeof(int) * N_EDGES);
    unsigned short* hbfA = (unsigned short*)alloc(sizeof(short) * (size_t)N_PAD * HID);
    unsigned short* hbfB = (unsigned short*)alloc(sizeof(short) * (size_t)N_PAD * HID);
    unsigned short* w1h  = (unsigned short*)alloc(sizeof(short) * HID * H2);
    unsigned short* w1l  = (unsigned short*)alloc(sizeof(short) * HID * H2);
    unsigned short* w2h  = (unsigned short*)alloc(sizeof(short) * H2 * HID);
    unsigned short* w2l  = (unsigned short*)alloc(sizeof(short) * H2 * HID);
    unsigned short* winh = (unsigned short*)alloc(sizeof(short) * HID * HID);
    unsigned short* winl = (unsigned short*)alloc(sizeof(short) * HID * HID);

    // weight packing (once per call)
    k_pack<<<16, 256, 0, stream>>>(W1, 128, 256, w1h, w1l);
    k_pack<<<16, 256, 0, stream>>>(W2, 256, 128, w2h, w2l);
    k_pack<<<8, 256, 0, stream>>>(W_in, 128, 128, winh, winl);

    // CSR build
    k_zero_counts<<<NB, 256, 0, stream>>>(counts);
    k_hist<<<(N_EDGES + 255) / 256, 256, 0, stream>>>(dst, counts);
    k_blocksum<<<NB, 256, 0, stream>>>(counts, bsum);
    k_scan_par<<<1, SCAN_B, 0, stream>>>(bsum, offsets);
    k_offsets<<<NB, 256, 0, stream>>>(counts, bsum, offsets, cursor);
    k_scatter<<<(N_EDGES + 255) / 256, 256, 0, stream>>>(src, dst, cursor, csr_src);

    // h0 (writes f32 h and bf16 hbfA)
    k_h0_mfma<<<NODE_BLOCKS, 256, 0, stream>>>(gat, winh, winl, b_in, h, hbfA);

    // 12 fused Euler steps; bf16 state ping-pongs, f32 h in place
    for (int s = 0; s < STEPS; s++) {
        const unsigned short* in = (s & 1) ? hbfB : hbfA;
        unsigned short*      out = (s & 1) ? hbfA : hbfB;
        k_step<<<NODE_BLOCKS, 512, 0, stream>>>(in, h, out, offsets, csr_src,
                                                w1h, w1l, b1, w2h, w2l, b2, clr);
    }
}